// Round 15
// baseline (401.127 us; speedup 1.0000x reference)
//
#include <hip/hip_runtime.h>
#include <cstdint>

typedef unsigned short u16;
typedef float  f32x4 __attribute__((ext_vector_type(4)));
typedef short  s16x4 __attribute__((ext_vector_type(4)));
typedef short  s16x8 __attribute__((ext_vector_type(8)));

#define D_IN  4096
#define D_OUT 4096
#define RMOE  128
#define KAUG  4224   /* D_IN + RMOE */
#define NTOK  8192   /* B*S = 4*2048 */

__device__ __forceinline__ u16 f2bf(float f) {
    unsigned u = __builtin_bit_cast(unsigned, f);
    unsigned r = u + 0x7fffu + ((u >> 16) & 1u);   // RNE
    return (u16)(r >> 16);
}

__device__ __forceinline__ void gload16(const void* g, void* l) {
    __builtin_amdgcn_global_load_lds(
        (const __attribute__((address_space(1))) void*)g,
        (__attribute__((address_space(3))) void*)l, 16, 0, 0);
}

// ---------------------------------------------------------------------------
// Kernel 1 (FUSED, validated R10): x fp32->bf16 into Xaug cols 0..4095 AND
// the fp32 router in one pass over x.
// ---------------------------------------------------------------------------
__global__ __launch_bounds__(256)
void xconv_router_kernel(const float* __restrict__ x, const float* __restrict__ rw,
                         const float* __restrict__ scal,
                         u16* __restrict__ Xaug, float* __restrict__ gates) {
    int wave = threadIdx.x >> 6, lane = threadIdx.x & 63;
    int t = blockIdx.x * 4 + wave;
    const float4* xp = (const float4*)(x + (long)t * D_IN);
    u16* xa = Xaug + (long)t * KAUG;
    float acc[8];
#pragma unroll
    for (int e = 0; e < 8; ++e) acc[e] = 0.f;
#pragma unroll 4
    for (int i = 0; i < 16; ++i) {
        float4 xv = xp[i * 64 + lane];
        s16x4 o;
        o[0] = (short)f2bf(xv.x); o[1] = (short)f2bf(xv.y);
        o[2] = (short)f2bf(xv.z); o[3] = (short)f2bf(xv.w);
        *(s16x4*)(xa + (i * 64 + lane) * 4) = o;
#pragma unroll
        for (int e = 0; e < 8; ++e) {
            float4 wv = ((const float4*)(rw + (long)e * D_IN))[i * 64 + lane];
            acc[e] += xv.x * wv.x + xv.y * wv.y + xv.z * wv.z + xv.w * wv.w;
        }
    }
#pragma unroll
    for (int e = 0; e < 8; ++e) {
#pragma unroll
        for (int off = 32; off > 0; off >>= 1)
            acc[e] += __shfl_xor(acc[e], off, 64);
    }
    if (lane == 0) {
        int i1 = 0; float v1 = acc[0];
#pragma unroll
        for (int e = 1; e < 8; ++e) if (acc[e] > v1) { v1 = acc[e]; i1 = e; }
        int i2 = -1; float v2 = -3.4e38f;
#pragma unroll
        for (int e = 0; e < 8; ++e) if (e != i1 && acc[e] > v2) { v2 = acc[e]; i2 = e; }
        float g1 = 1.f / (1.f + expf(v2 - v1));
        float g2 = 1.f - g1;
        float* gp = gates + (long)t * 8;
#pragma unroll
        for (int e = 0; e < 8; ++e)
            gp[e] = (e == i1) ? g1 * scal[e] : ((e == i2) ? g2 * scal[e] : 0.f);
    }
}

// ---------------------------------------------------------------------------
// Kernel 2 (validated R10): remaining conversions — bw, lora_B, lora_A.
// ---------------------------------------------------------------------------
__global__ __launch_bounds__(256)
void convert_rest_kernel(const float* __restrict__ bw,
                         const float* __restrict__ lA, const float* __restrict__ lB,
                         u16* __restrict__ Waug, u16* __restrict__ A16) {
    const long nw = (long)D_OUT * D_IN / 8;   // 2,097,152
    const long nb = (long)D_OUT * RMOE / 8;   // 65,536
    long tid = (long)blockIdx.x * 256 + threadIdx.x;
    const float* src; u16* dst;
    if (tid < nw) {
        long e = tid * 8; long row = e >> 12; long col = e & 4095;
        src = bw + e; dst = Waug + row * KAUG + col;
    } else if (tid < nw + nb) {
        long e = (tid - nw) * 8; long row = e >> 7; long col = e & 127;
        src = lB + e; dst = Waug + row * KAUG + D_IN + col;
    } else {
        long e = (tid - nw - nb) * 8;
        src = lA + e; dst = A16 + e;
    }
    float4 a = ((const float4*)src)[0];
    float4 b = ((const float4*)src)[1];
    s16x8 o;
    o[0] = (short)f2bf(a.x); o[1] = (short)f2bf(a.y);
    o[2] = (short)f2bf(a.z); o[3] = (short)f2bf(a.w);
    o[4] = (short)f2bf(b.x); o[5] = (short)f2bf(b.y);
    o[6] = (short)f2bf(b.z); o[7] = (short)f2bf(b.w);
    *(s16x8*)dst = o;
}

// ---------------------------------------------------------------------------
// Kernel 3: h_scaled = (x @ lora_A^T) * gate, bf16 into Xaug cols 4096..4223.
// (unchanged, validated)
// ---------------------------------------------------------------------------
__global__ __launch_bounds__(256)
void lora_h_kernel(u16* __restrict__ Xaug, const u16* __restrict__ A16,
                   const float* __restrict__ gates) {
    __shared__ u16 sX[64 * 32];
    __shared__ u16 sW[64 * 32];
    int tid = threadIdx.x, wave = tid >> 6, lane = tid & 63;
    int bm = blockIdx.x >> 1, bn = blockIdx.x & 1;
    long m0 = (long)bm * 64; int n0 = bn * 64;
    int wr = wave >> 1, wc = wave & 1;
    int c = wave * 64 + lane, row = c >> 2, oct = c & 3;
    const u16* gx = Xaug + (m0 + row) * KAUG + oct * 8;
    const u16* gw = A16 + (long)(n0 + row) * D_IN + oct * 8;
    u16* lx = sX + wave * 512;
    u16* lw = sW + wave * 512;
    int cl = lane & 15, kh = lane >> 4;
    int aoff[2], boff[2];
#pragma unroll
    for (int i = 0; i < 2; ++i) {
        aoff[i] = (wr * 32 + i * 16 + cl) * 32 + kh * 8;
        boff[i] = (wc * 32 + i * 16 + cl) * 32 + kh * 8;
    }
    f32x4 acc[2][2];
#pragma unroll
    for (int i = 0; i < 2; ++i)
#pragma unroll
        for (int j = 0; j < 2; ++j) acc[i][j] = (f32x4){0.f, 0.f, 0.f, 0.f};
    for (int kt = 0; kt < 128; ++kt) {
        __syncthreads();
        gload16(gx, lx); gload16(gw, lw);
        gx += 32; gw += 32;
        __syncthreads();
        s16x8 a[2], b[2];
#pragma unroll
        for (int i = 0; i < 2; ++i) {
            a[i] = *(const s16x8*)&sX[aoff[i]];
            b[i] = *(const s16x8*)&sW[boff[i]];
        }
#pragma unroll
        for (int mi = 0; mi < 2; ++mi)
#pragma unroll
            for (int ni = 0; ni < 2; ++ni)
                acc[mi][ni] = __builtin_amdgcn_mfma_f32_16x16x32_bf16(
                    a[mi], b[ni], acc[mi][ni], 0, 0, 0);
    }
#pragma unroll
    for (int ni = 0; ni < 2; ++ni) {
        int col = n0 + wc * 32 + ni * 16 + cl;
        int g = col >> 4;
#pragma unroll
        for (int mi = 0; mi < 2; ++mi) {
#pragma unroll
            for (int r = 0; r < 4; ++r) {
                long tok = m0 + wr * 32 + mi * 16 + kh * 4 + r;
                float v = acc[mi][ni][r] * gates[tok * 8 + g];
                Xaug[tok * KAUG + D_IN + col] = f2bf(v);
            }
        }
    }
}

// ---------------------------------------------------------------------------
// Kernel 4: main GEMM, 256x256 tile, BK=32, 8 waves (2Mx4N), 4-deep LDS
// pipeline, counted vmcnt (T4) + XCD swizzle (T1) + T2 LDS swizzle.
//
// ROUND-15 CHANGE: LEAD-1 MODULO SCHEDULE (2 phases/tile, per-phase barrier).
// Each phase reads the NEXT phase's operands, then MFMAs the CURRENT ones —
// reads issued before a barrier are serviced while other waves MFMA
// (LDS pipe || MFMA pipe overlap via wave stagger).
//   P0(t): vmcnt(8); bar; stageA(t+3); read A-hi(t)[4]; lgkm(4); MFMA m0-3
//   P1(t): vmcnt(6); bar; stageB(t+3); read B(t+1)+A-lo(t+1)[8]; lgkm(8);
//          MFMA m4-7
// vmcnt ledger (2 loads/phase staging, 3-tile lead): at P0, loads younger
// than st(t) = 8; at P1, younger than st(t+1) = 6 — never near-drain.
// lgkm(4)/(8) drain exactly the previous phase's reads (>=600 cyc cover).
// Overwrite safety as validated (R13): stage hits buf[(t-1)&3]; its readers
// finished >=1 barrier earlier. Tail: t=131 skips next-reads, lgkm(0).
// Ping-pong register sets via 2x-unrolled loop (rule #20).
// ---------------------------------------------------------------------------
__global__ __launch_bounds__(512, 2)
void main_gemm(const u16* __restrict__ Xaug, const u16* __restrict__ Waug,
               const float* __restrict__ bias, float* __restrict__ out) {
    __shared__ u16 lds[4 * 16384];     // 128 KiB
    const int tid = threadIdx.x;
    const int wave = tid >> 6, lane = tid & 63;
    const int cl = lane & 15, kh = lane >> 4;
    const int wr = wave >> 2, wc = wave & 3;

    // T1: bijective XCD swizzle (512 blocks, 512 % 8 == 0)
    int bid = blockIdx.x;
    int swz = (bid & 7) * 64 + (bid >> 3);
    long m0 = (long)(swz & 31) * 256;   // 32 M-blocks
    long n0 = (long)(swz >> 5) * 256;   // 16 N-blocks

    const int rA = tid >> 2;
    const int sl = (((tid & 3) ^ ((tid >> 3) & 3))) * 8;
    const u16* gA0 = Xaug + (m0 + rA) * KAUG + sl;
    const u16* gA1 = Xaug + (m0 + 128 + rA) * KAUG + sl;
    const u16* gB0 = Waug + (n0 + rA) * KAUG + sl;
    const u16* gB1 = Waug + (n0 + 128 + rA) * KAUG + sl;
    const int wbase = wave * 512;       // wave-uniform LDS base (el)

    const int swk = (kh ^ ((cl >> 1) & 3)) * 8;
    const int aob = (wr * 128 + cl) * 32 + swk;
    const int bob = 8192 + (wc * 64 + cl) * 32 + swk;

    f32x4 acc[8][4];
#pragma unroll
    for (int m = 0; m < 8; ++m)
#pragma unroll
        for (int n = 0; n < 4; ++n) acc[m][n] = (f32x4){0.f, 0.f, 0.f, 0.f};

#define STAGE_A(t) do { u16* L = lds + ((t) & 3) * 16384 + wbase;            \
        gload16(gA0 + (t) * 32, L);                                          \
        gload16(gA1 + (t) * 32, L + 4096); } while (0)
#define STAGE_B(t) do { u16* L = lds + ((t) & 3) * 16384 + wbase;            \
        gload16(gB0 + (t) * 32, L + 8192);                                   \
        gload16(gB1 + (t) * 32, L + 12288); } while (0)
#define RD_AHI(av, Lb) do {                                                  \
        av[4] = *(const s16x8*)&(Lb)[aob + 2048];                            \
        av[5] = *(const s16x8*)&(Lb)[aob + 2560];                            \
        av[6] = *(const s16x8*)&(Lb)[aob + 3072];                            \
        av[7] = *(const s16x8*)&(Lb)[aob + 3584]; } while (0)
#define RD_BALO(av, bv, Lb) do {                                             \
        bv[0] = *(const s16x8*)&(Lb)[bob];                                   \
        bv[1] = *(const s16x8*)&(Lb)[bob + 512];                             \
        bv[2] = *(const s16x8*)&(Lb)[bob + 1024];                            \
        bv[3] = *(const s16x8*)&(Lb)[bob + 1536];                            \
        av[0] = *(const s16x8*)&(Lb)[aob];                                   \
        av[1] = *(const s16x8*)&(Lb)[aob + 512];                             \
        av[2] = *(const s16x8*)&(Lb)[aob + 1024];                            \
        av[3] = *(const s16x8*)&(Lb)[aob + 1536]; } while (0)
#define CL_LO(av, bv) do {                                                   \
        __builtin_amdgcn_s_setprio(1);                                       \
        _Pragma("unroll")                                                    \
        for (int m_ = 0; m_ < 4; ++m_)                                       \
            _Pragma("unroll")                                                \
            for (int n_ = 0; n_ < 4; ++n_)                                   \
                acc[m_][n_] = __builtin_amdgcn_mfma_f32_16x16x32_bf16(       \
                    av[m_], bv[n_], acc[m_][n_], 0, 0, 0);                   \
        __builtin_amdgcn_s_setprio(0); } while (0)
#define CL_HI(av, bv) do {                                                   \
        __builtin_amdgcn_s_setprio(1);                                       \
        _Pragma("unroll")                                                    \
        for (int m_ = 4; m_ < 8; ++m_)                                       \
            _Pragma("unroll")                                                \
            for (int n_ = 0; n_ < 4; ++n_)                                   \
                acc[m_][n_] = __builtin_amdgcn_mfma_f32_16x16x32_bf16(       \
                    av[m_], bv[n_], acc[m_][n_], 0, 0, 0);                   \
        __builtin_amdgcn_s_setprio(0); } while (0)
#define SBAR() __builtin_amdgcn_sched_barrier(0)

// one tile, 2 phases, lead-1 reads into (avN,bvN)
#define TILE(t, avC, bvC, avN, bvN) do {                                     \
        /* P0 */                                                             \
        asm volatile("s_waitcnt vmcnt(8)" ::: "memory");                     \
        __builtin_amdgcn_s_barrier();                                        \
        SBAR();                                                              \
        if ((t) + 3 < 132) STAGE_A((t) + 3);                                 \
        { const u16* LbT = lds + ((t) & 3) * 16384; RD_AHI(avC, LbT); }      \
        asm volatile("s_waitcnt lgkmcnt(4)" ::: "memory");                   \
        SBAR();                                                              \
        CL_LO(avC, bvC);                                                     \
        /* P1 */                                                             \
        asm volatile("s_waitcnt vmcnt(6)" ::: "memory");                     \
        __builtin_amdgcn_s_barrier();                                        \
        SBAR();                                                              \
        if ((t) + 3 < 132) STAGE_B((t) + 3);                                 \
        if ((t) < 131) {                                                     \
            const u16* LbN = lds + (((t) + 1) & 3) * 16384;                  \
            RD_BALO(avN, bvN, LbN);                                          \
            asm volatile("s_waitcnt lgkmcnt(8)" ::: "memory");               \
        } else {                                                             \
            asm volatile("s_waitcnt lgkmcnt(0)" ::: "memory");               \
        }                                                                    \
        SBAR();                                                              \
        CL_HI(avC, bvC); } while (0)

    s16x8 av0[8], bv0[4], av1[8], bv1[4];

    // prologue: stage tiles 0..2 (12 loads), gate tile 0, read its lo-set
    STAGE_A(0); STAGE_B(0);
    STAGE_A(1); STAGE_B(1);
    STAGE_A(2); STAGE_B(2);
    asm volatile("s_waitcnt vmcnt(8)" ::: "memory");   // st(0) landed
    __builtin_amdgcn_s_barrier();
    SBAR();
    RD_BALO(av0, bv0, (lds + 0));                      // B(0) + A-lo(0)

    for (int u = 0; u < 66; ++u) {
        TILE(2 * u,     av0, bv0, av1, bv1);
        TILE(2 * u + 1, av1, bv1, av0, bv0);
    }
#undef STAGE_A
#undef STAGE_B
#undef RD_AHI
#undef RD_BALO
#undef CL_LO
#undef CL_HI
#undef SBAR
#undef TILE

#pragma unroll
    for (int n = 0; n < 4; ++n) {
        long col = n0 + wc * 64 + n * 16 + cl;
        float bvv = bias[col];
#pragma unroll
        for (int m = 0; m < 8; ++m) {
            long row = m0 + wr * 128 + m * 16 + kh * 4;
#pragma unroll
            for (int r = 0; r < 4; ++r)
                out[(row + r) * (long)D_OUT + col] = acc[m][n][r] + bvv;
        }
    }
}

// ---------------------------------------------------------------------------
extern "C" void kernel_launch(void* const* d_in, const int* in_sizes, int n_in,
                              void* d_out, int out_size, void* d_ws, size_t ws_size,
                              hipStream_t stream) {
    const float* x  = (const float*)d_in[0];
    const float* bw = (const float*)d_in[1];
    const float* bb = (const float*)d_in[2];
    const float* lA = (const float*)d_in[3];
    const float* lB = (const float*)d_in[4];
    const float* rw = (const float*)d_in[5];
    const float* sc = (const float*)d_in[6];
    float* out = (float*)d_out;

    char* ws = (char*)d_ws;
    u16* Xaug  = (u16*)ws;                      // 8192*4224*2 = 69,206,016 B
    u16* Waug  = (u16*)(ws + 69206016);         // 4096*4224*2 = 34,603,008 B
    u16* A16   = (u16*)(ws + 103809024);        // 128*4096*2  =  1,048,576 B
    float* gates = (float*)(ws + 104857600);    // 8192*8*4    =    262,144 B

    xconv_router_kernel<<<2048, 256, 0, stream>>>(x, rw, sc, Xaug, gates);
    convert_rest_kernel<<<8704, 256, 0, stream>>>(bw, lA, lB, Waug, A16);
    lora_h_kernel<<<256, 256, 0, stream>>>(Xaug, A16, gates);
    main_gemm<<<512, 512, 0, stream>>>(Xaug, Waug, bb, out);
}

// Round 18
// 388.253 us; speedup vs baseline: 1.0332x; 1.0332x over previous
//
#include <hip/hip_runtime.h>
#include <cstdint>

typedef unsigned short u16;
typedef float  f32x4 __attribute__((ext_vector_type(4)));
typedef short  s16x4 __attribute__((ext_vector_type(4)));
typedef short  s16x8 __attribute__((ext_vector_type(8)));

#define D_IN  4096
#define D_OUT 4096
#define RMOE  128
#define KAUG  4224   /* D_IN + RMOE */
#define NTOK  8192   /* B*S = 4*2048 */

__device__ __forceinline__ u16 f2bf(float f) {
    unsigned u = __builtin_bit_cast(unsigned, f);
    unsigned r = u + 0x7fffu + ((u >> 16) & 1u);   // RNE
    return (u16)(r >> 16);
}

__device__ __forceinline__ void gload16(const void* g, void* l) {
    __builtin_amdgcn_global_load_lds(
        (const __attribute__((address_space(1))) void*)g,
        (__attribute__((address_space(3))) void*)l, 16, 0, 0);
}

// ---------------------------------------------------------------------------
// Kernel 1 (HORIZONTAL FUSION): blocks 0..2047 = x-convert+router
// (byte-identical logic to validated xconv_router); blocks 2048..10751 =
// bw/lora_B/lora_A conversions (byte-identical to validated convert_rest).
// Router blocks first: they are the long pole; convert blocks (pure HBM BW)
// fill the machine behind them.
// ---------------------------------------------------------------------------
__global__ __launch_bounds__(256)
void prep_kernel(const float* __restrict__ x, const float* __restrict__ rw,
                 const float* __restrict__ scal, const float* __restrict__ bw,
                 const float* __restrict__ lA, const float* __restrict__ lB,
                 u16* __restrict__ Xaug, u16* __restrict__ Waug,
                 u16* __restrict__ A16, float* __restrict__ gates) {
    if (blockIdx.x < 2048) {
        // ---- router + x conversion (validated R10 logic) ----
        int wave = threadIdx.x >> 6, lane = threadIdx.x & 63;
        int t = blockIdx.x * 4 + wave;
        const float4* xp = (const float4*)(x + (long)t * D_IN);
        u16* xa = Xaug + (long)t * KAUG;
        float acc[8];
#pragma unroll
        for (int e = 0; e < 8; ++e) acc[e] = 0.f;
#pragma unroll 4
        for (int i = 0; i < 16; ++i) {
            float4 xv = xp[i * 64 + lane];
            s16x4 o;
            o[0] = (short)f2bf(xv.x); o[1] = (short)f2bf(xv.y);
            o[2] = (short)f2bf(xv.z); o[3] = (short)f2bf(xv.w);
            *(s16x4*)(xa + (i * 64 + lane) * 4) = o;
#pragma unroll
            for (int e = 0; e < 8; ++e) {
                float4 wv = ((const float4*)(rw + (long)e * D_IN))[i * 64 + lane];
                acc[e] += xv.x * wv.x + xv.y * wv.y + xv.z * wv.z + xv.w * wv.w;
            }
        }
#pragma unroll
        for (int e = 0; e < 8; ++e) {
#pragma unroll
            for (int off = 32; off > 0; off >>= 1)
                acc[e] += __shfl_xor(acc[e], off, 64);
        }
        if (lane == 0) {
            int i1 = 0; float v1 = acc[0];
#pragma unroll
            for (int e = 1; e < 8; ++e) if (acc[e] > v1) { v1 = acc[e]; i1 = e; }
            int i2 = -1; float v2 = -3.4e38f;
#pragma unroll
            for (int e = 0; e < 8; ++e) if (e != i1 && acc[e] > v2) { v2 = acc[e]; i2 = e; }
            float g1 = 1.f / (1.f + expf(v2 - v1));
            float g2 = 1.f - g1;
            float* gp = gates + (long)t * 8;
#pragma unroll
            for (int e = 0; e < 8; ++e)
                gp[e] = (e == i1) ? g1 * scal[e] : ((e == i2) ? g2 * scal[e] : 0.f);
        }
    } else {
        // ---- bw / lora_B / lora_A conversions (validated R10 logic) ----
        const long nw = (long)D_OUT * D_IN / 8;   // 2,097,152
        const long nb = (long)D_OUT * RMOE / 8;   // 65,536
        long tid = (long)(blockIdx.x - 2048) * 256 + threadIdx.x;
        const float* src; u16* dst;
        if (tid < nw) {
            long e = tid * 8; long row = e >> 12; long col = e & 4095;
            src = bw + e; dst = Waug + row * KAUG + col;
        } else if (tid < nw + nb) {
            long e = (tid - nw) * 8; long row = e >> 7; long col = e & 127;
            src = lB + e; dst = Waug + row * KAUG + D_IN + col;
        } else {
            long e = (tid - nw - nb) * 8;
            src = lA + e; dst = A16 + e;
        }
        float4 a = ((const float4*)src)[0];
        float4 b = ((const float4*)src)[1];
        s16x8 o;
        o[0] = (short)f2bf(a.x); o[1] = (short)f2bf(a.y);
        o[2] = (short)f2bf(a.z); o[3] = (short)f2bf(a.w);
        o[4] = (short)f2bf(b.x); o[5] = (short)f2bf(b.y);
        o[6] = (short)f2bf(b.z); o[7] = (short)f2bf(b.w);
        *(s16x8*)dst = o;
    }
}

// ---------------------------------------------------------------------------
// Kernel 2: lora_h with BM=64, BN=32 -> grid 512 (2 blocks/CU) to halve
// exposed staging latency (was 256 blocks, latency-bound). A-tile (64x32)
// staged by all 4 waves; B-tile (32x32 of A16) by waves 0-1 only
// (wave-uniform gload_lds base preserved; guard tid<128 is wave-uniform).
// Wave (wr,wc) owns a 32x16 output sub-tile: acc 2x1 frags of 16x16x32.
// ---------------------------------------------------------------------------
__global__ __launch_bounds__(256)
void lora_h_kernel(u16* __restrict__ Xaug, const u16* __restrict__ A16,
                   const float* __restrict__ gates) {
    __shared__ u16 sX[64 * 32];
    __shared__ u16 sW[32 * 32];
    int tid = threadIdx.x, wave = tid >> 6, lane = tid & 63;
    int bm = blockIdx.x >> 2, bn = blockIdx.x & 3;     // 128 x 4
    long m0 = (long)bm * 64; int n0 = bn * 32;
    int wr = wave >> 1, wc = wave & 1;
    int rowA = tid >> 2, oct = tid & 3;
    const u16* gx = Xaug + (m0 + rowA) * KAUG + oct * 8;
    const u16* gw = A16 + (long)(n0 + rowA) * D_IN + oct * 8;  // used only rowA<32
    u16* lx = sX + wave * 512;   // wave-uniform base; lane x 16B appended by HW
    u16* lw = sW + wave * 512;   // only waves 0,1 stage B
    int cl = lane & 15, kh = lane >> 4;
    int aoff[2];
#pragma unroll
    for (int i = 0; i < 2; ++i)
        aoff[i] = (wr * 32 + i * 16 + cl) * 32 + kh * 8;
    int boff = (wc * 16 + cl) * 32 + kh * 8;
    f32x4 acc2[2];
    acc2[0] = (f32x4){0.f, 0.f, 0.f, 0.f};
    acc2[1] = (f32x4){0.f, 0.f, 0.f, 0.f};
    for (int kt = 0; kt < 128; ++kt) {
        __syncthreads();
        gload16(gx, lx);
        if (tid < 128) gload16(gw, lw);
        gx += 32; gw += 32;
        __syncthreads();
        s16x8 a[2], b;
        a[0] = *(const s16x8*)&sX[aoff[0]];
        a[1] = *(const s16x8*)&sX[aoff[1]];
        b = *(const s16x8*)&sW[boff];
#pragma unroll
        for (int mi = 0; mi < 2; ++mi)
            acc2[mi] = __builtin_amdgcn_mfma_f32_16x16x32_bf16(
                a[mi], b, acc2[mi], 0, 0, 0);
    }
    int col = n0 + wc * 16 + cl;     // rank 0..127
    int g = col >> 4;
#pragma unroll
    for (int mi = 0; mi < 2; ++mi) {
#pragma unroll
        for (int r = 0; r < 4; ++r) {
            long tok = m0 + wr * 32 + mi * 16 + kh * 4 + r;
            float v = acc2[mi][r] * gates[tok * 8 + g];
            Xaug[tok * KAUG + D_IN + col] = f2bf(v);
        }
    }
}

// ---------------------------------------------------------------------------
// Kernel 3: main GEMM — EXACT R13 body (best measured: 253.7 us, MfmaUtil 53,
// conflicts 0). 256x256 tile, BK=32, 8 waves, 4-deep LDS pipeline, counted
// vmcnt (T4) + XCD swizzle (T1) + T2 swizzle + register read-ahead.
// ---------------------------------------------------------------------------
__global__ __launch_bounds__(512, 2)
void main_gemm(const u16* __restrict__ Xaug, const u16* __restrict__ Waug,
               const float* __restrict__ bias, float* __restrict__ out) {
    __shared__ u16 lds[4 * 16384];     // 128 KiB
    const int tid = threadIdx.x;
    const int wave = tid >> 6, lane = tid & 63;
    const int cl = lane & 15, kh = lane >> 4;
    const int wr = wave >> 2, wc = wave & 3;

    int bid = blockIdx.x;
    int swz = (bid & 7) * 64 + (bid >> 3);
    long m0 = (long)(swz & 31) * 256;   // 32 M-blocks
    long n0 = (long)(swz >> 5) * 256;   // 16 N-blocks

    const int rA = tid >> 2;
    const int sl = (((tid & 3) ^ ((tid >> 3) & 3))) * 8;
    const u16* gA0 = Xaug + (m0 + rA) * KAUG + sl;
    const u16* gA1 = Xaug + (m0 + 128 + rA) * KAUG + sl;
    const u16* gB0 = Waug + (n0 + rA) * KAUG + sl;
    const u16* gB1 = Waug + (n0 + 128 + rA) * KAUG + sl;
    const int wbase = wave * 512;

    const int swk = (kh ^ ((cl >> 1) & 3)) * 8;
    const int aob = (wr * 128 + cl) * 32 + swk;
    const int bob = 8192 + (wc * 64 + cl) * 32 + swk;

    f32x4 acc[8][4];
#pragma unroll
    for (int m = 0; m < 8; ++m)
#pragma unroll
        for (int n = 0; n < 4; ++n) acc[m][n] = (f32x4){0.f, 0.f, 0.f, 0.f};

#define STAGE(t) do { u16* L = lds + ((t) & 3) * 16384 + wbase;              \
        gload16(gA0 + (t) * 32, L);                                          \
        gload16(gA1 + (t) * 32, L + 4096);                                   \
        gload16(gB0 + (t) * 32, L + 8192);                                   \
        gload16(gB1 + (t) * 32, L + 12288); } while (0)
#define READL(av, bv, Lb) do {                                               \
        _Pragma("unroll")                                                    \
        for (int m_ = 0; m_ < 8; ++m_)                                       \
            av[m_] = *(const s16x8*)&(Lb)[aob + m_ * 512];                   \
        _Pragma("unroll")                                                    \
        for (int n_ = 0; n_ < 4; ++n_)                                       \
            bv[n_] = *(const s16x8*)&(Lb)[bob + n_ * 512]; } while (0)
#define DOMFMA(av, bv) do {                                                  \
        __builtin_amdgcn_s_setprio(1);                                       \
        _Pragma("unroll")                                                    \
        for (int m_ = 0; m_ < 8; ++m_)                                       \
            _Pragma("unroll")                                                \
            for (int n_ = 0; n_ < 4; ++n_)                                   \
                acc[m_][n_] = __builtin_amdgcn_mfma_f32_16x16x32_bf16(       \
                    av[m_], bv[n_], acc[m_][n_], 0, 0, 0);                   \
        __builtin_amdgcn_s_setprio(0); } while (0)

    s16x8 av0[8], bv0[4], av1[8], bv1[4];

    STAGE(0); STAGE(1); STAGE(2);                 // 12 loads in flight
    asm volatile("s_waitcnt vmcnt(8)" ::: "memory");   // tile 0 landed
    __builtin_amdgcn_s_barrier();
    __builtin_amdgcn_sched_barrier(0);
    READL(av0, bv0, (lds + 0));                   // tile 0 operands

    for (int u = 0; u < 66; ++u) {
        const int tA = 2 * u, tB = 2 * u + 1;
        if (tA <= 128) asm volatile("s_waitcnt vmcnt(4)" ::: "memory");
        else           asm volatile("s_waitcnt vmcnt(0)" ::: "memory");
        __builtin_amdgcn_s_barrier();
        __builtin_amdgcn_sched_barrier(0);
        {
            const u16* Lb = lds + (tB & 3) * 16384;
            READL(av1, bv1, Lb);
            if (tA + 3 < 132) STAGE(tA + 3);
        }
        asm volatile("s_waitcnt lgkmcnt(12)" ::: "memory");
        __builtin_amdgcn_sched_barrier(0);
        DOMFMA(av0, bv0);
        if (tB < 131) {
            asm volatile("s_waitcnt vmcnt(4)" ::: "memory");
            __builtin_amdgcn_s_barrier();
            __builtin_amdgcn_sched_barrier(0);
            {
                const u16* Lb = lds + ((tB + 1) & 3) * 16384;
                READL(av0, bv0, Lb);
                if (tB + 3 < 132) STAGE(tB + 3);
            }
            asm volatile("s_waitcnt lgkmcnt(12)" ::: "memory");
            __builtin_amdgcn_sched_barrier(0);
        } else {
            asm volatile("s_waitcnt lgkmcnt(0)" ::: "memory");
            __builtin_amdgcn_sched_barrier(0);
        }
        DOMFMA(av1, bv1);
    }
#undef STAGE
#undef READL
#undef DOMFMA

#pragma unroll
    for (int n = 0; n < 4; ++n) {
        long col = n0 + wc * 64 + n * 16 + cl;
        float bvv = bias[col];
#pragma unroll
        for (int m = 0; m < 8; ++m) {
            long row = m0 + wr * 128 + m * 16 + kh * 4;
#pragma unroll
            for (int r = 0; r < 4; ++r)
                out[(row + r) * (long)D_OUT + col] = acc[m][n][r] + bvv;
        }
    }
}

// ---------------------------------------------------------------------------
extern "C" void kernel_launch(void* const* d_in, const int* in_sizes, int n_in,
                              void* d_out, int out_size, void* d_ws, size_t ws_size,
                              hipStream_t stream) {
    const float* x  = (const float*)d_in[0];
    const float* bw = (const float*)d_in[1];
    const float* bb = (const float*)d_in[2];
    const float* lA = (const float*)d_in[3];
    const float* lB = (const float*)d_in[4];
    const float* rw = (const float*)d_in[5];
    const float* sc = (const float*)d_in[6];
    float* out = (float*)d_out;

    char* ws = (char*)d_ws;
    u16* Xaug  = (u16*)ws;                      // 8192*4224*2 = 69,206,016 B
    u16* Waug  = (u16*)(ws + 69206016);         // 4096*4224*2 = 34,603,008 B
    u16* A16   = (u16*)(ws + 103809024);        // 128*4096*2  =  1,048,576 B
    float* gates = (float*)(ws + 104857600);    // 8192*8*4    =    262,144 B

    prep_kernel<<<10752, 256, 0, stream>>>(x, rw, sc, bw, lA, lB,
                                           Xaug, Waug, A16, gates);
    lora_h_kernel<<<512, 256, 0, stream>>>(Xaug, A16, gates);
    main_gemm<<<512, 512, 0, stream>>>(Xaug, Waug, bb, out);
}